// Round 1
// baseline (257.199 us; speedup 1.0000x reference)
//
#include <hip/hip_runtime.h>
#include <math.h>

#define NH    8
#define DIM   256
#define NQ    8400
#define BATCH 4
#define STOT  8400
#define MQ    (BATCH * NQ)   // 33600

typedef _Float16 f16;
typedef __attribute__((ext_vector_type(2))) _Float16 f16x2;
typedef __attribute__((ext_vector_type(8))) _Float16 f16x8;
typedef __attribute__((ext_vector_type(4))) float  f32x4;

// Async global->LDS, 16B per lane. LDS dest is wave-uniform base + lane*16.
static __device__ __forceinline__ void gl_lds16(const void* g, void* l) {
    __builtin_amdgcn_global_load_lds(
        (const __attribute__((address_space(1))) unsigned int*)g,
        (__attribute__((address_space(3))) unsigned int*)(unsigned int)(unsigned long long)l,
        16, 0, 0);
}

// ---------------------------------------------------------------------------
// prep_w: weight transposes fp32 [K,N] -> fp16 [N,K] + bias concat. Tiny.
__global__ __launch_bounds__(256) void prep_w(
    const float* __restrict__ W_val, const float* __restrict__ W_out,
    const float* __restrict__ W_off, const float* __restrict__ W_attn,
    const float* __restrict__ b_off, const float* __restrict__ b_attn,
    f16* __restrict__ Wvt, f16* __restrict__ Wot, f16* __restrict__ Wch,
    float* __restrict__ bcat)
{
    const int xb = blockIdx.x;
    const int t = threadIdx.x;
    __shared__ float tile[32][33];
    const int c = t & 31, r = t >> 5;

    if (xb == 25) {
        if (blockIdx.y == 0)
            for (int i = t; i < 288; i += 256)
                bcat[i] = (i < 192) ? b_off[i] : b_attn[i - 192];
        return;
    }
    const float* W; f16* oH; int Nw, n0, nb;
    if (xb < 8)       { W = W_val;  oH = Wvt; Nw = 256; n0 = 0;   nb = xb * 32; }
    else if (xb < 16) { W = W_out;  oH = Wot; Nw = 256; n0 = 0;   nb = (xb - 8) * 32; }
    else if (xb < 22) { W = W_off;  oH = Wch; Nw = 192; n0 = 0;   nb = (xb - 16) * 32; }
    else              { W = W_attn; oH = Wch; Nw = 96;  n0 = 192; nb = (xb - 22) * 32; }
    const int k0 = blockIdx.y * 32;
    #pragma unroll
    for (int i = 0; i < 4; ++i) {
        int k = k0 + r + i * 8, n = nb + c;
        tile[r + i * 8][c] = (n < Nw) ? W[(size_t)k * Nw + n] : 0.f;
    }
    __syncthreads();
    #pragma unroll
    for (int i = 0; i < 4; ++i) {
        int n = nb + r + i * 8, k = k0 + c;
        if (n < Nw)
            oH[(size_t)(n0 + n) * 256 + k] = (f16)tile[c][r + i * 8];
    }
}

// ---------------------------------------------------------------------------
// GEMM with fused input layout conversion.
// KIND 0, x<2  (val): A reg-staged from fp32 feat [B,256,S] (transpose+cvt on
//                     the fly) into padded pitch-40 LDS (no XOR needed).
// KIND 0, x>=2 (raw): A reg-staged from fp32 query [MQ,256] (cvt on the fly).
// KIND 1       (out): A fp16 via global_load_lds, pitch-32 XOR layout.
// B always fp16 via global_load_lds, pitch-32 XOR layout.
template<int KIND>
__global__ __launch_bounds__(256) void gemm_fused(
    const float* __restrict__ feat0, const float* __restrict__ feat1,
    const float* __restrict__ feat2, const float* __restrict__ query,
    const f16* __restrict__ A16,
    const f16* __restrict__ B0, const f16* __restrict__ B1,
    const float* __restrict__ bias0, const float* __restrict__ bias1,
    f16* __restrict__ valh, float* __restrict__ rawo, f16* __restrict__ attnh,
    float* __restrict__ Cf)
{
    __shared__ __align__(16) f16 Ahs[128 * 40];  // KIND0 pitch-40; KIND1 uses 128*32
    __shared__ __align__(16) f16 Bs[128 * 32];

    const bool split = (KIND == 0) && (blockIdx.x >= 2);
    const int bn = split ? (blockIdx.x - 2) * 128 : blockIdx.x * 128;
    const int bm = blockIdx.y * 128;
    const int N = split ? 288 : 256;
    const f16* Bg = split ? B1 : B0;
    const float* bias = split ? bias1 : bias0;

    const int t = threadIdx.x;
    const int lane = t & 63, w = t >> 6;
    const int wm = (w & 1) * 64, wn = (w >> 1) * 64;
    const int l15 = lane & 15, quad = lane >> 4;

    // XOR chunk swizzle constants (gl_lds16 paths only)
    const int fstage = ((t >> 2) & 3) ^ ((t >> 4) & 3);
    const int qs = (t & 3) ^ fstage;
    const int ffrag = (l15 & 3) ^ ((l15 >> 2) & 3);
    const int qf = quad ^ ffrag;

    // val-path A staging setup: thread owns s-row pair (2*spair, 2*spair+1),
    // k-chunk kqA. Pairs never straddle a level/batch boundary (all even).
    const float* aptr = nullptr; int Sv = 0;
    int rA0 = 0, kqA = 0;
    if (KIND == 0 && !split) {
        const int spair = t >> 2;
        kqA = t & 3;
        rA0 = spair * 2;
        int gr = bm + rA0;
        if (gr + 1 >= MQ) gr = MQ - 2;           // stays even; dup rows are discarded
        int bb = gr / STOT, s = gr - bb * STOT;
        if (s < 6400)      { aptr = feat0 + (size_t)bb * 256 * 6400 + s;          Sv = 6400; }
        else if (s < 8000) { aptr = feat1 + (size_t)bb * 256 * 1600 + (s - 6400); Sv = 1600; }
        else               { aptr = feat2 + (size_t)bb * 256 * 400  + (s - 8000); Sv = 400;  }
    }

    f32x4 acc[4][4];
    #pragma unroll
    for (int i = 0; i < 4; ++i)
        #pragma unroll
        for (int j = 0; j < 4; ++j)
            acc[i][j] = (f32x4){0.f, 0.f, 0.f, 0.f};

    for (int k0 = 0; k0 < 256; k0 += 32) {
        if (KIND == 0 && !split) {
            // 8 coalesced float2 loads (contiguous along s), cvt, 2x ds_write_b128
            float2 va[8];
            #pragma unroll
            for (int j = 0; j < 8; ++j)
                va[j] = *(const float2*)(aptr + (size_t)(k0 + kqA * 8 + j) * Sv);
            f16x8 h0, h1;
            #pragma unroll
            for (int j = 0; j < 8; ++j) { h0[j] = (f16)va[j].x; h1[j] = (f16)va[j].y; }
            *(f16x8*)&Ahs[((rA0)     * 5 + kqA) * 8] = h0;
            *(f16x8*)&Ahs[((rA0 + 1) * 5 + kqA) * 8] = h1;
        } else if (KIND == 0) {
            #pragma unroll
            for (int i = 0; i < 2; ++i) {
                int row = i * 64 + (t >> 2), q4 = t & 3;
                int gr = bm + row; if (gr > MQ - 1) gr = MQ - 1;
                const float* qp = query + (size_t)gr * 256 + k0 + q4 * 8;
                float4 a = *(const float4*)qp;
                float4 b = *(const float4*)(qp + 4);
                f16x8 h;
                h[0] = (f16)a.x; h[1] = (f16)a.y; h[2] = (f16)a.z; h[3] = (f16)a.w;
                h[4] = (f16)b.x; h[5] = (f16)b.y; h[6] = (f16)b.z; h[7] = (f16)b.w;
                *(f16x8*)&Ahs[(row * 5 + q4) * 8] = h;
            }
        } else {
            #pragma unroll
            for (int i = 0; i < 2; ++i) {
                int row = i * 64 + (t >> 2), slot = i * 256 + t;
                int gr = bm + row; if (gr > MQ - 1) gr = MQ - 1;
                gl_lds16(A16 + (size_t)gr * 256 + k0 + qs * 8, &Ahs[slot * 8]);
            }
        }
        #pragma unroll
        for (int i = 0; i < 2; ++i) {
            int row = i * 64 + (t >> 2), slot = i * 256 + t;
            int gn = bn + row; if (gn > N - 1) gn = N - 1;
            gl_lds16(Bg + (size_t)gn * 256 + k0 + qs * 8, &Bs[slot * 8]);
        }
        __syncthreads();

        f16x8 af[4], bfv[4];
        #pragma unroll
        for (int mt = 0; mt < 4; ++mt) {
            int ar = wm + mt * 16 + l15;
            af[mt] = (KIND == 0)
                ? *(const f16x8*)&Ahs[(ar * 5 + quad) * 8]
                : *(const f16x8*)&Ahs[(ar * 4 + qf) * 8];
        }
        #pragma unroll
        for (int nt = 0; nt < 4; ++nt)
            bfv[nt] = *(const f16x8*)&Bs[((wn + nt * 16 + l15) * 4 + qf) * 8];
        #pragma unroll
        for (int mt = 0; mt < 4; ++mt)
            #pragma unroll
            for (int nt = 0; nt < 4; ++nt)
                acc[mt][nt] = __builtin_amdgcn_mfma_f32_16x16x32_f16(af[mt], bfv[nt], acc[mt][nt], 0, 0, 0);
        __syncthreads();
    }

    #pragma unroll
    for (int nt = 0; nt < 4; ++nt) {
        int col = bn + wn + nt * 16 + l15;
        float bv = (col < N) ? bias[col] : 0.f;
        #pragma unroll
        for (int mt = 0; mt < 4; ++mt) {
            int row0 = bm + wm + mt * 16 + quad * 4;
            #pragma unroll
            for (int r = 0; r < 4; ++r) {
                int row = row0 + r;
                if (row >= MQ || col >= N) continue;
                float v = acc[mt][nt][r] + bv;
                if (KIND == 1) {
                    Cf[(size_t)row * 256 + col] = v;
                } else if (!split) {
                    int bb = row / STOT, s = row - bb * STOT;
                    int h = col >> 5, c = col & 31;
                    valh[(((size_t)(bb * 8 + h)) * STOT + s) * 32 + c] = (f16)v;
                } else if (col < 192) {
                    rawo[(size_t)row * 192 + col] = 0.5f * tanhf(v);  // tanh moved out of sampler
                } else {
                    attnh[(size_t)row * 96 + (col - 192)] = (f16)v;
                }
            }
        }
    }
}

// ---------------------------------------------------------------------------
// Sampler v7: packed (w16|idx16) LDS (12.8KB -> higher occupancy), tanh
// pre-applied upstream, packed-fp16 inner loop, fp32 flush per 12 corners.
__global__ __launch_bounds__(256) void sample_v7(
    const f16* __restrict__ valh,        // [B*8][STOT][32] fp16
    const float* __restrict__ off05,     // [MQ][192] = 0.5*tanh(raw)+0 (fp32)
    const f16* __restrict__ attnh,       // [MQ][96] fp16
    const float* __restrict__ refp,      // [MQ][2]
    f16* __restrict__ out_h)             // [MQ][256] fp16
{
    const int bx = blockIdx.x;
    const int xcd = bx & 7;
    const int b = xcd >> 1;
    const int qi = (bx >> 3) * 2 + (xcd & 1);
    const int bq0 = b * NQ + qi * 8;
    const int t = threadIdx.x;

    __shared__ unsigned s_pk[8][96][4];   // (w16<<16)|idx16 per corner
    __shared__ float    s_m[8][8];
    __shared__ float    s_inv[8][8];

    if (t < 64) {
        int q = t >> 3, h = t & 7;
        const f16* a = attnh + (size_t)(bq0 + q) * 96 + h * 12;
        float m = (float)a[0];
        #pragma unroll
        for (int j = 1; j < 12; ++j) m = fmaxf(m, (float)a[j]);
        float s = 0.f;
        #pragma unroll
        for (int j = 0; j < 12; ++j) s += expf((float)a[j] - m);
        s_m[q][h] = m;
        s_inv[q][h] = 1.f / s;
    }
    __syncthreads();

    for (int i = t; i < 768; i += 256) {
        int q = i / 96, p = i - q * 96;
        int h = p / 12, lp = p - h * 12, l = lp >> 2;
        const int dims[3]   = {80, 40, 20};
        const int bases_[3] = {0, 6400, 8000};
        int Wl = dims[l], base = bases_[l];
        float logit = (float)attnh[(size_t)(bq0 + q) * 96 + p];
        float aw = expf(logit - s_m[q][h]) * s_inv[q][h];
        size_t ro = (size_t)(bq0 + q) * 192 + h * 24 + lp * 2;
        float ox = off05[ro], oy = off05[ro + 1];
        float rx = refp[(size_t)(bq0 + q) * 2];
        float ry = refp[(size_t)(bq0 + q) * 2 + 1];
        float ix = (rx + ox) * Wl - 0.5f;
        float iy = (ry + oy) * Wl - 0.5f;
        float x0f = floorf(ix), y0f = floorf(iy);
        float fx = ix - x0f, fy = iy - y0f;
        int x0 = (int)x0f, y0 = (int)y0f;
        float w00 = (1.f - fx) * (1.f - fy) * aw;
        float w01 = fx * (1.f - fy) * aw;
        float w10 = (1.f - fx) * fy * aw;
        float w11 = fx * fy * aw;
        bool vx0 = (unsigned)x0 < (unsigned)Wl;
        bool vx1 = (unsigned)(x0 + 1) < (unsigned)Wl;
        bool vy0 = (unsigned)y0 < (unsigned)Wl;
        bool vy1 = (unsigned)(y0 + 1) < (unsigned)Wl;
        int row0 = base + y0 * Wl, row1 = row0 + Wl;
        float ws[4] = { vx0 && vy0 ? w00 : 0.f, vx1 && vy0 ? w01 : 0.f,
                        vx0 && vy1 ? w10 : 0.f, vx1 && vy1 ? w11 : 0.f };
        int   is[4] = { vx0 && vy0 ? row0 + x0 : 0, vx1 && vy0 ? row0 + x0 + 1 : 0,
                        vx0 && vy1 ? row1 + x0 : 0, vx1 && vy1 ? row1 + x0 + 1 : 0 };
        #pragma unroll
        for (int k = 0; k < 4; ++k) {
            unsigned short us = __builtin_bit_cast(unsigned short, (f16)ws[k]);
            s_pk[q][p][k] = ((unsigned)us << 16) | (unsigned)is[k];
        }
    }
    __syncthreads();

    const int q = t >> 5;
    const int h = (t >> 2) & 7;
    const int l4 = t & 3;
    const uint4* vb4 = (const uint4*)(valh + (size_t)(b * 8 + h) * STOT * 32);
    const unsigned* pkp = &s_pk[q][h * 12][0];
    float accf[8] = {};
    #pragma unroll
    for (int pp = 0; pp < 4; ++pp) {
        unsigned pk[12]; uint4 v[12];
        #pragma unroll
        for (int k = 0; k < 12; ++k) pk[k] = pkp[pp * 12 + k];
        #pragma unroll
        for (int k = 0; k < 12; ++k) v[k] = vb4[(size_t)(pk[k] & 0xffffu) * 4 + l4];
        f16x2 a0 = (f16x2)(f16)0, a1 = a0, a2 = a0, a3 = a0;
        #pragma unroll
        for (int k = 0; k < 12; ++k) {
            // (w,w) from packed word via v_perm_b32 (bytes 2,3,2,3)
            f16x2 wv = __builtin_bit_cast(f16x2,
                        __builtin_amdgcn_perm(pk[k], pk[k], 0x03020302u));
            a0 += wv * __builtin_bit_cast(f16x2, v[k].x);
            a1 += wv * __builtin_bit_cast(f16x2, v[k].y);
            a2 += wv * __builtin_bit_cast(f16x2, v[k].z);
            a3 += wv * __builtin_bit_cast(f16x2, v[k].w);
        }
        accf[0] += (float)a0[0]; accf[1] += (float)a0[1];
        accf[2] += (float)a1[0]; accf[3] += (float)a1[1];
        accf[4] += (float)a2[0]; accf[5] += (float)a2[1];
        accf[6] += (float)a3[0]; accf[7] += (float)a3[1];
    }
    f16x8 ob;
    #pragma unroll
    for (int c = 0; c < 8; ++c) ob[c] = (f16)accf[c];
    *(f16x8*)(out_h + (size_t)(bq0 + q) * 256 + h * 32 + l4 * 8) = ob;
}

// ---------------------------------------------------------------------------
extern "C" void kernel_launch(void* const* d_in, const int* in_sizes, int n_in,
                              void* d_out, int out_size, void* d_ws, size_t ws_size,
                              hipStream_t stream)
{
    const float* query  = (const float*)d_in[0];
    const float* feat0  = (const float*)d_in[1];
    const float* feat1  = (const float*)d_in[2];
    const float* feat2  = (const float*)d_in[3];
    const float* refp   = (const float*)d_in[4];
    const float* W_off  = (const float*)d_in[5];
    const float* b_off  = (const float*)d_in[6];
    const float* W_attn = (const float*)d_in[7];
    const float* b_attn = (const float*)d_in[8];
    const float* W_val  = (const float*)d_in[9];
    const float* b_val  = (const float*)d_in[10];
    const float* W_out  = (const float*)d_in[11];
    const float* b_out  = (const float*)d_in[12];
    float* out = (float*)d_out;

    // workspace (~67 MB)
    f16*   valh  = (f16*)d_ws;                               // MQ*256 fp16
    float* rawo  = (float*)(valh + (size_t)MQ * 256);        // MQ*192 f32 (tanh'd*0.5)
    f16*   attnh = (f16*)(rawo + (size_t)MQ * 192);          // MQ*96 fp16
    f16*   outh  = attnh + (size_t)MQ * 96;                  // MQ*256 fp16
    f16*   Wvt   = outh + (size_t)MQ * 256;                  // 256*256
    f16*   Wot   = Wvt + 65536;
    f16*   Wch   = Wot + 65536;                              // 288*256
    float* bcat  = (float*)(Wch + 73728);

    dim3 blk(256);

    prep_w<<<dim3(26, 8), blk, 0, stream>>>(W_val, W_out, W_off, W_attn,
                                            b_off, b_attn, Wvt, Wot, Wch, bcat);
    gemm_fused<0><<<dim3(5, 263), blk, 0, stream>>>(feat0, feat1, feat2, query, nullptr,
                                                    Wvt, Wch, b_val, bcat,
                                                    valh, rawo, attnh, nullptr);
    sample_v7<<<dim3(MQ / 8), blk, 0, stream>>>(valh, rawo, attnh, refp, outh);
    gemm_fused<1><<<dim3(2, 263), blk, 0, stream>>>(feat0, feat1, feat2, query, outh,
                                                    Wot, nullptr, b_out, nullptr,
                                                    nullptr, nullptr, nullptr, out);
}

// Round 2
// 248.434 us; speedup vs baseline: 1.0353x; 1.0353x over previous
//
#include <hip/hip_runtime.h>
#include <math.h>

#define NH    8
#define DIM   256
#define NQ    8400
#define BATCH 4
#define STOT  8400
#define MQ    (BATCH * NQ)   // 33600

typedef _Float16 f16;
typedef __attribute__((ext_vector_type(2))) _Float16 f16x2;
typedef __attribute__((ext_vector_type(8))) _Float16 f16x8;
typedef __attribute__((ext_vector_type(4))) float  f32x4;

// Async global->LDS, 16B per lane. LDS dest is wave-uniform base + lane*16.
static __device__ __forceinline__ void gl_lds16(const void* g, void* l) {
    __builtin_amdgcn_global_load_lds(
        (const __attribute__((address_space(1))) unsigned int*)g,
        (__attribute__((address_space(3))) unsigned int*)(unsigned int)(unsigned long long)l,
        16, 0, 0);
}

// ---------------------------------------------------------------------------
// prep_w: weight transposes fp32 [K,N] -> fp16 [N,K] + bias concat. Tiny.
__global__ __launch_bounds__(256) void prep_w(
    const float* __restrict__ W_val, const float* __restrict__ W_out,
    const float* __restrict__ W_off, const float* __restrict__ W_attn,
    const float* __restrict__ b_off, const float* __restrict__ b_attn,
    f16* __restrict__ Wvt, f16* __restrict__ Wot, f16* __restrict__ Wch,
    float* __restrict__ bcat)
{
    const int xb = blockIdx.x;
    const int t = threadIdx.x;
    __shared__ float tile[32][33];
    const int c = t & 31, r = t >> 5;

    if (xb == 25) {
        if (blockIdx.y == 0)
            for (int i = t; i < 288; i += 256)
                bcat[i] = (i < 192) ? b_off[i] : b_attn[i - 192];
        return;
    }
    const float* W; f16* oH; int Nw, n0, nb;
    if (xb < 8)       { W = W_val;  oH = Wvt; Nw = 256; n0 = 0;   nb = xb * 32; }
    else if (xb < 16) { W = W_out;  oH = Wot; Nw = 256; n0 = 0;   nb = (xb - 8) * 32; }
    else if (xb < 22) { W = W_off;  oH = Wch; Nw = 192; n0 = 0;   nb = (xb - 16) * 32; }
    else              { W = W_attn; oH = Wch; Nw = 96;  n0 = 192; nb = (xb - 22) * 32; }
    const int k0 = blockIdx.y * 32;
    #pragma unroll
    for (int i = 0; i < 4; ++i) {
        int k = k0 + r + i * 8, n = nb + c;
        tile[r + i * 8][c] = (n < Nw) ? W[(size_t)k * Nw + n] : 0.f;
    }
    __syncthreads();
    #pragma unroll
    for (int i = 0; i < 4; ++i) {
        int n = nb + r + i * 8, k = k0 + c;
        if (n < Nw)
            oH[(size_t)(n0 + n) * 256 + k] = (f16)tile[c][r + i * 8];
    }
}

// ---------------------------------------------------------------------------
// GEMM with fused input layout conversion, 2-phase double-buffered pipeline:
// per K-step: issue next-tile loads -> ds_read+MFMA on current -> cvt+ds_write
// next A tile -> single __syncthreads (vmcnt drain covered by MFMA phase).
// KIND 0, x<2  (val): A reg-staged from fp32 feat (transpose+cvt), pitch-40 LDS.
// KIND 0, x>=2 (raw): A reg-staged from fp32 query (cvt), pitch-40 LDS.
// KIND 1       (out): A fp16 via global_load_lds, pitch-32 XOR layout.
// B always fp16 via global_load_lds, pitch-32 XOR layout.
template<int KIND>
__global__ __launch_bounds__(256) void gemm_fused(
    const float* __restrict__ feat0, const float* __restrict__ feat1,
    const float* __restrict__ feat2, const float* __restrict__ query,
    const f16* __restrict__ A16,
    const f16* __restrict__ B0, const f16* __restrict__ B1,
    const float* __restrict__ bias0, const float* __restrict__ bias1,
    f16* __restrict__ valh, float* __restrict__ rawo, f16* __restrict__ attnh,
    float* __restrict__ Cf)
{
    __shared__ __align__(16) f16 Ahs[2][128 * 40];  // KIND0 pitch-40; KIND1 pitch-32
    __shared__ __align__(16) f16 Bs[2][128 * 32];

    const bool split = (KIND == 0) && (blockIdx.x >= 2);
    const int bn = split ? (blockIdx.x - 2) * 128 : blockIdx.x * 128;
    const int bm = blockIdx.y * 128;
    const int N = split ? 288 : 256;
    const f16* Bg = split ? B1 : B0;
    const float* bias = split ? bias1 : bias0;

    const int t = threadIdx.x;
    const int lane = t & 63, w = t >> 6;
    const int wm = (w & 1) * 64, wn = (w >> 1) * 64;
    const int l15 = lane & 15, quad = lane >> 4;

    // XOR chunk swizzle constants (gl_lds16 paths only)
    const int fstage = ((t >> 2) & 3) ^ ((t >> 4) & 3);
    const int qs = (t & 3) ^ fstage;
    const int ffrag = (l15 & 3) ^ ((l15 >> 2) & 3);
    const int qf = quad ^ ffrag;

    // val-path A staging setup: thread owns s-row pair (2*spair, 2*spair+1),
    // k-chunk kqA. Pairs never straddle a level/batch boundary (all even).
    const float* aptr = nullptr; int Sv = 0;
    int rA0 = 0;
    const int kqA = t & 3;
    if (KIND == 0 && !split) {
        rA0 = (t >> 2) * 2;
        int gr = bm + rA0;
        if (gr + 1 >= MQ) gr = MQ - 2;           // stays even; dup rows discarded
        int bb = gr / STOT, s = gr - bb * STOT;
        if (s < 6400)      { aptr = feat0 + (size_t)bb * 256 * 6400 + s;          Sv = 6400; }
        else if (s < 8000) { aptr = feat1 + (size_t)bb * 256 * 1600 + (s - 6400); Sv = 1600; }
        else               { aptr = feat2 + (size_t)bb * 256 * 400  + (s - 8000); Sv = 400;  }
    }

    float2 va[8];    // val-path in-flight A regs
    float4 qa[4];    // query-path in-flight A regs

    auto loadA_val = [&](int k0) {
        #pragma unroll
        for (int j = 0; j < 8; ++j)
            va[j] = *(const float2*)(aptr + (size_t)(k0 + kqA * 8 + j) * Sv);
    };
    auto writeA_val = [&](int buf) {
        f16x8 h0, h1;
        #pragma unroll
        for (int j = 0; j < 8; ++j) { h0[j] = (f16)va[j].x; h1[j] = (f16)va[j].y; }
        *(f16x8*)&Ahs[buf][((rA0)     * 5 + kqA) * 8] = h0;
        *(f16x8*)&Ahs[buf][((rA0 + 1) * 5 + kqA) * 8] = h1;
    };
    auto loadA_q = [&](int k0) {
        #pragma unroll
        for (int i = 0; i < 2; ++i) {
            int row = i * 64 + (t >> 2);
            int gr = bm + row; if (gr > MQ - 1) gr = MQ - 1;
            const float* qp = query + (size_t)gr * 256 + k0 + kqA * 8;
            qa[i * 2]     = *(const float4*)qp;
            qa[i * 2 + 1] = *(const float4*)(qp + 4);
        }
    };
    auto writeA_q = [&](int buf) {
        #pragma unroll
        for (int i = 0; i < 2; ++i) {
            int row = i * 64 + (t >> 2);
            float4 a = qa[i * 2], b = qa[i * 2 + 1];
            f16x8 h;
            h[0] = (f16)a.x; h[1] = (f16)a.y; h[2] = (f16)a.z; h[3] = (f16)a.w;
            h[4] = (f16)b.x; h[5] = (f16)b.y; h[6] = (f16)b.z; h[7] = (f16)b.w;
            *(f16x8*)&Ahs[buf][(row * 5 + kqA) * 8] = h;
        }
    };
    auto stageA_lds = [&](int k0, int buf) {
        #pragma unroll
        for (int i = 0; i < 2; ++i) {
            int row = i * 64 + (t >> 2), slot = i * 256 + t;
            int gr = bm + row; if (gr > MQ - 1) gr = MQ - 1;
            gl_lds16(A16 + (size_t)gr * 256 + k0 + qs * 8, &Ahs[buf][slot * 8]);
        }
    };
    auto stageB = [&](int k0, int buf) {
        #pragma unroll
        for (int i = 0; i < 2; ++i) {
            int row = i * 64 + (t >> 2), slot = i * 256 + t;
            int gn = bn + row; if (gn > N - 1) gn = N - 1;
            gl_lds16(Bg + (size_t)gn * 256 + k0 + qs * 8, &Bs[buf][slot * 8]);
        }
    };

    f32x4 acc[4][4];
    #pragma unroll
    for (int i = 0; i < 4; ++i)
        #pragma unroll
        for (int j = 0; j < 4; ++j)
            acc[i][j] = (f32x4){0.f, 0.f, 0.f, 0.f};

    // ---- prologue: stage K-tile 0 into buffer 0
    if (KIND == 0 && !split)      { loadA_val(0); stageB(0, 0); writeA_val(0); }
    else if (KIND == 0)           { loadA_q(0);   stageB(0, 0); writeA_q(0); }
    else                          { stageA_lds(0, 0); stageB(0, 0); }
    __syncthreads();

    #pragma unroll
    for (int kt = 0; kt < 8; ++kt) {
        const int cur = kt & 1, nxt = cur ^ 1;
        const int k0n = (kt + 1) * 32;
        // issue next-tile loads FIRST (A before B so the va-use wait leaves B in flight)
        if (kt < 7) {
            if (KIND == 0 && !split)  loadA_val(k0n);
            else if (KIND == 0)       loadA_q(k0n);
            else                      stageA_lds(k0n, nxt);
            stageB(k0n, nxt);
        }
        // compute on current buffer
        f16x8 af[4], bfv[4];
        #pragma unroll
        for (int mt = 0; mt < 4; ++mt) {
            int ar = wm + mt * 16 + l15;
            af[mt] = (KIND == 0)
                ? *(const f16x8*)&Ahs[cur][(ar * 5 + quad) * 8]
                : *(const f16x8*)&Ahs[cur][(ar * 4 + qf) * 8];
        }
        #pragma unroll
        for (int nt = 0; nt < 4; ++nt)
            bfv[nt] = *(const f16x8*)&Bs[cur][((wn + nt * 16 + l15) * 4 + qf) * 8];
        #pragma unroll
        for (int mt = 0; mt < 4; ++mt)
            #pragma unroll
            for (int nt = 0; nt < 4; ++nt)
                acc[mt][nt] = __builtin_amdgcn_mfma_f32_16x16x32_f16(af[mt], bfv[nt], acc[mt][nt], 0, 0, 0);
        // write next A tile (regs -> LDS) late, then one barrier per K-step
        if (kt < 7) {
            if (KIND == 0 && !split)  writeA_val(nxt);
            else if (KIND == 0)       writeA_q(nxt);
            __syncthreads();
        }
    }

    #pragma unroll
    for (int nt = 0; nt < 4; ++nt) {
        int col = bn + wn + nt * 16 + l15;
        float bv = (col < N) ? bias[col] : 0.f;
        #pragma unroll
        for (int mt = 0; mt < 4; ++mt) {
            int row0 = bm + wm + mt * 16 + quad * 4;
            #pragma unroll
            for (int r = 0; r < 4; ++r) {
                int row = row0 + r;
                if (row >= MQ || col >= N) continue;
                float v = acc[mt][nt][r] + bv;
                if (KIND == 1) {
                    Cf[(size_t)row * 256 + col] = v;
                } else if (!split) {
                    int bb = row / STOT, s = row - bb * STOT;
                    int h = col >> 5, c = col & 31;
                    valh[(((size_t)(bb * 8 + h)) * STOT + s) * 32 + c] = (f16)v;
                } else if (col < 192) {
                    rawo[(size_t)row * 192 + col] = 0.5f * tanhf(v);  // tanh hoisted out of sampler
                } else {
                    attnh[(size_t)row * 96 + (col - 192)] = (f16)v;
                }
            }
        }
    }
}

// ---------------------------------------------------------------------------
// Sampler v7: packed (w16|idx16) LDS (12.8KB -> higher occupancy), tanh
// pre-applied upstream, packed-fp16 inner loop, fp32 flush per 12 corners.
__global__ __launch_bounds__(256) void sample_v7(
    const f16* __restrict__ valh,        // [B*8][STOT][32] fp16
    const float* __restrict__ off05,     // [MQ][192] = 0.5*tanh(raw) (fp32)
    const f16* __restrict__ attnh,       // [MQ][96] fp16
    const float* __restrict__ refp,      // [MQ][2]
    f16* __restrict__ out_h)             // [MQ][256] fp16
{
    const int bx = blockIdx.x;
    const int xcd = bx & 7;
    const int b = xcd >> 1;
    const int qi = (bx >> 3) * 2 + (xcd & 1);
    const int bq0 = b * NQ + qi * 8;
    const int t = threadIdx.x;

    __shared__ unsigned s_pk[8][96][4];   // (w16<<16)|idx16 per corner
    __shared__ float    s_m[8][8];
    __shared__ float    s_inv[8][8];

    if (t < 64) {
        int q = t >> 3, h = t & 7;
        const f16* a = attnh + (size_t)(bq0 + q) * 96 + h * 12;
        float m = (float)a[0];
        #pragma unroll
        for (int j = 1; j < 12; ++j) m = fmaxf(m, (float)a[j]);
        float s = 0.f;
        #pragma unroll
        for (int j = 0; j < 12; ++j) s += expf((float)a[j] - m);
        s_m[q][h] = m;
        s_inv[q][h] = 1.f / s;
    }
    __syncthreads();

    for (int i = t; i < 768; i += 256) {
        int q = i / 96, p = i - q * 96;
        int h = p / 12, lp = p - h * 12, l = lp >> 2;
        const int dims[3]   = {80, 40, 20};
        const int bases_[3] = {0, 6400, 8000};
        int Wl = dims[l], base = bases_[l];
        float logit = (float)attnh[(size_t)(bq0 + q) * 96 + p];
        float aw = expf(logit - s_m[q][h]) * s_inv[q][h];
        size_t ro = (size_t)(bq0 + q) * 192 + h * 24 + lp * 2;
        float ox = off05[ro], oy = off05[ro + 1];
        float rx = refp[(size_t)(bq0 + q) * 2];
        float ry = refp[(size_t)(bq0 + q) * 2 + 1];
        float ix = (rx + ox) * Wl - 0.5f;
        float iy = (ry + oy) * Wl - 0.5f;
        float x0f = floorf(ix), y0f = floorf(iy);
        float fx = ix - x0f, fy = iy - y0f;
        int x0 = (int)x0f, y0 = (int)y0f;
        float w00 = (1.f - fx) * (1.f - fy) * aw;
        float w01 = fx * (1.f - fy) * aw;
        float w10 = (1.f - fx) * fy * aw;
        float w11 = fx * fy * aw;
        bool vx0 = (unsigned)x0 < (unsigned)Wl;
        bool vx1 = (unsigned)(x0 + 1) < (unsigned)Wl;
        bool vy0 = (unsigned)y0 < (unsigned)Wl;
        bool vy1 = (unsigned)(y0 + 1) < (unsigned)Wl;
        int row0 = base + y0 * Wl, row1 = row0 + Wl;
        float ws[4] = { vx0 && vy0 ? w00 : 0.f, vx1 && vy0 ? w01 : 0.f,
                        vx0 && vy1 ? w10 : 0.f, vx1 && vy1 ? w11 : 0.f };
        int   is[4] = { vx0 && vy0 ? row0 + x0 : 0, vx1 && vy0 ? row0 + x0 + 1 : 0,
                        vx0 && vy1 ? row1 + x0 : 0, vx1 && vy1 ? row1 + x0 + 1 : 0 };
        #pragma unroll
        for (int k = 0; k < 4; ++k) {
            unsigned short us = __builtin_bit_cast(unsigned short, (f16)ws[k]);
            s_pk[q][p][k] = ((unsigned)us << 16) | (unsigned)is[k];
        }
    }
    __syncthreads();

    const int q = t >> 5;
    const int h = (t >> 2) & 7;
    const int l4 = t & 3;
    const uint4* vb4 = (const uint4*)(valh + (size_t)(b * 8 + h) * STOT * 32);
    const unsigned* pkp = &s_pk[q][h * 12][0];
    float accf[8] = {};
    #pragma unroll
    for (int pp = 0; pp < 4; ++pp) {
        unsigned pk[12]; uint4 v[12];
        #pragma unroll
        for (int k = 0; k < 12; ++k) pk[k] = pkp[pp * 12 + k];
        #pragma unroll
        for (int k = 0; k < 12; ++k) v[k] = vb4[(size_t)(pk[k] & 0xffffu) * 4 + l4];
        f16x2 a0 = (f16x2)(f16)0, a1 = a0, a2 = a0, a3 = a0;
        #pragma unroll
        for (int k = 0; k < 12; ++k) {
            // (w,w) from packed word via v_perm_b32 (bytes 2,3,2,3)
            f16x2 wv = __builtin_bit_cast(f16x2,
                        __builtin_amdgcn_perm(pk[k], pk[k], 0x03020302u));
            a0 += wv * __builtin_bit_cast(f16x2, v[k].x);
            a1 += wv * __builtin_bit_cast(f16x2, v[k].y);
            a2 += wv * __builtin_bit_cast(f16x2, v[k].z);
            a3 += wv * __builtin_bit_cast(f16x2, v[k].w);
        }
        accf[0] += (float)a0[0]; accf[1] += (float)a0[1];
        accf[2] += (float)a1[0]; accf[3] += (float)a1[1];
        accf[4] += (float)a2[0]; accf[5] += (float)a2[1];
        accf[6] += (float)a3[0]; accf[7] += (float)a3[1];
    }
    f16x8 ob;
    #pragma unroll
    for (int c = 0; c < 8; ++c) ob[c] = (f16)accf[c];
    *(f16x8*)(out_h + (size_t)(bq0 + q) * 256 + h * 32 + l4 * 8) = ob;
}

// ---------------------------------------------------------------------------
extern "C" void kernel_launch(void* const* d_in, const int* in_sizes, int n_in,
                              void* d_out, int out_size, void* d_ws, size_t ws_size,
                              hipStream_t stream)
{
    const float* query  = (const float*)d_in[0];
    const float* feat0  = (const float*)d_in[1];
    const float* feat1  = (const float*)d_in[2];
    const float* feat2  = (const float*)d_in[3];
    const float* refp   = (const float*)d_in[4];
    const float* W_off  = (const float*)d_in[5];
    const float* b_off  = (const float*)d_in[6];
    const float* W_attn = (const float*)d_in[7];
    const float* b_attn = (const float*)d_in[8];
    const float* W_val  = (const float*)d_in[9];
    const float* b_val  = (const float*)d_in[10];
    const float* W_out  = (const float*)d_in[11];
    const float* b_out  = (const float*)d_in[12];
    float* out = (float*)d_out;

    // workspace (~67 MB)
    f16*   valh  = (f16*)d_ws;                               // MQ*256 fp16
    float* rawo  = (float*)(valh + (size_t)MQ * 256);        // MQ*192 f32 (tanh'd*0.5)
    f16*   attnh = (f16*)(rawo + (size_t)MQ * 192);          // MQ*96 fp16
    f16*   outh  = attnh + (size_t)MQ * 96;                  // MQ*256 fp16
    f16*   Wvt   = outh + (size_t)MQ * 256;                  // 256*256
    f16*   Wot   = Wvt + 65536;
    f16*   Wch   = Wot + 65536;                              // 288*256
    float* bcat  = (float*)(Wch + 73728);

    dim3 blk(256);

    prep_w<<<dim3(26, 8), blk, 0, stream>>>(W_val, W_out, W_off, W_attn,
                                            b_off, b_attn, Wvt, Wot, Wch, bcat);
    gemm_fused<0><<<dim3(5, 263), blk, 0, stream>>>(feat0, feat1, feat2, query, nullptr,
                                                    Wvt, Wch, b_val, bcat,
                                                    valh, rawo, attnh, nullptr);
    sample_v7<<<dim3(MQ / 8), blk, 0, stream>>>(valh, rawo, attnh, refp, outh);
    gemm_fused<1><<<dim3(2, 263), blk, 0, stream>>>(feat0, feat1, feat2, query, outh,
                                                    Wot, nullptr, b_out, nullptr,
                                                    nullptr, nullptr, nullptr, out);
}